// Round 1
// baseline (617.896 us; speedup 1.0000x reference)
//
#include <hip/hip_runtime.h>
#include <hip/hip_bf16.h>

typedef float f32x4 __attribute__((ext_vector_type(4)));
typedef short s16x8 __attribute__((ext_vector_type(8)));

#define F_IN 256
#define F_OUT 64

static __device__ __forceinline__ short f2bf(float f){
  union { float f; unsigned u; } x; x.f = f;
  unsigned r = (x.u + 0x7FFFu + ((x.u >> 16) & 1u)) >> 16;
  return (short)r;
}

// ---------------- degree / CSR build ----------------

__global__ void hist_kernel(const int* __restrict__ ei, int E, int* __restrict__ deg,
                            int* __restrict__ counts){
  int e = blockIdx.x * blockDim.x + threadIdx.x;
  if (e >= E) return;
  int r = ei[e], c = ei[E + e];
  if (r != c) atomicAdd(&deg[r], 1);
  atomicAdd(&counts[c], 1);
}

__global__ void dis_kernel(const int* __restrict__ deg, float* __restrict__ dis,
                           float* __restrict__ selfnorm, int n){
  int i = blockIdx.x * blockDim.x + threadIdx.x;
  if (i >= n) return;
  float d = (float)(deg[i] + 1);   // +1: appended self-loop
  dis[i] = rsqrtf(d);
  selfnorm[i] = 1.0f / d;
}

// single-block exclusive scan of counts[n] -> offsets[n+1], cursors[n]
__global__ __launch_bounds__(1024) void scan_kernel(const int* __restrict__ counts,
                                                    int* __restrict__ offsets,
                                                    int* __restrict__ cursors, int n){
  const int C = 10;  // 1024*10 >= 10000
  __shared__ int lds[1024];
  int tid = threadIdx.x;
  int base = tid * C;
  int s = 0;
  for (int i = 0; i < C; ++i){ int idx = base + i; if (idx < n) s += counts[idx]; }
  lds[tid] = s; __syncthreads();
  for (int off = 1; off < 1024; off <<= 1){
    int add = (tid >= off) ? lds[tid - off] : 0;
    __syncthreads();
    lds[tid] += add;
    __syncthreads();
  }
  int run = lds[tid] - s;  // exclusive prefix
  for (int i = 0; i < C; ++i){
    int idx = base + i;
    if (idx < n){ offsets[idx] = run; cursors[idx] = run; run += counts[idx]; }
  }
  if (tid == 1023) offsets[n] = lds[1023];
}

__global__ void fill_kernel(const int* __restrict__ ei, int E, const float* __restrict__ dis,
                            int* __restrict__ cursors, int* __restrict__ csr_row,
                            float* __restrict__ csr_norm){
  int e = blockIdx.x * blockDim.x + threadIdx.x;
  if (e >= E) return;
  int r = ei[e], c = ei[E + e];
  int pos = atomicAdd(&cursors[c], 1);
  csr_row[pos] = r;
  csr_norm[pos] = (r == c) ? 0.0f : dis[r] * dis[c];
}

// ---------------- feature GEMM: Y[slab by][n][64] = X @ W_by ----------------
// X [M,256] f32, W [1280,64] f32, grid (ceil(M/64), 5), 256 threads

__global__ __launch_bounds__(256) void fgemm_kernel(const float* __restrict__ X,
                                                    const float* __restrict__ W,
                                                    float* __restrict__ Y, int M){
  __shared__ float As[32][68];  // k-major, padded (272B rows, 16B aligned)
  __shared__ float Bs[32][68];
  int t = threadIdx.x;
  int bx = blockIdx.x, by = blockIdx.y;
  int row0 = bx * 64;
  int tx = t & 15, ty = t >> 4;
  f32x4 acc[4] = {{0,0,0,0},{0,0,0,0},{0,0,0,0},{0,0,0,0}};
  for (int k0 = 0; k0 < F_IN; k0 += 32){
    {
      int m = t >> 2, kk = (t & 3) * 8;
      int gr = row0 + m;
      f32x4 v0 = {0,0,0,0}, v1 = {0,0,0,0};
      if (gr < M){
        const float* p = X + (size_t)gr * F_IN + k0 + kk;
        v0 = *(const f32x4*)p; v1 = *(const f32x4*)(p + 4);
      }
      As[kk+0][m] = v0[0]; As[kk+1][m] = v0[1]; As[kk+2][m] = v0[2]; As[kk+3][m] = v0[3];
      As[kk+4][m] = v1[0]; As[kk+5][m] = v1[1]; As[kk+6][m] = v1[2]; As[kk+7][m] = v1[3];
    }
    {
      int kk = t >> 3, c = (t & 7) * 8;
      const float* p = W + (size_t)(by * 256 + k0 + kk) * 64 + c;
      f32x4 v0 = *(const f32x4*)p, v1 = *(const f32x4*)(p + 4);
      *(f32x4*)&Bs[kk][c] = v0; *(f32x4*)&Bs[kk][c + 4] = v1;
    }
    __syncthreads();
    #pragma unroll
    for (int kk = 0; kk < 32; ++kk){
      f32x4 a = *(const f32x4*)&As[kk][ty * 4];
      f32x4 b = *(const f32x4*)&Bs[kk][tx * 4];
      #pragma unroll
      for (int i = 0; i < 4; ++i)
        #pragma unroll
        for (int j = 0; j < 4; ++j)
          acc[i][j] += a[i] * b[j];
    }
    __syncthreads();
  }
  size_t slab = (size_t)by * M * 64;
  #pragma unroll
  for (int i = 0; i < 4; ++i){
    int gr = row0 + ty * 4 + i;
    if (gr < M) *(f32x4*)&Y[slab + (size_t)gr * 64 + tx * 4] = acc[i];
  }
}

// ---------------- sparse propagate: tout = Yk + A * tin ----------------
// one wave per node, lane = feature

__global__ __launch_bounds__(256) void gather_kernel(const float* __restrict__ Yk,
    const float* __restrict__ tin, const int* __restrict__ offsets,
    const int* __restrict__ csr_row, const float* __restrict__ csr_norm,
    const float* __restrict__ selfnorm, float* __restrict__ tout, int n){
  int wid = threadIdx.x >> 6, lane = threadIdx.x & 63;
  int node = blockIdx.x * 4 + wid;
  if (node >= n) return;
  int e0 = offsets[node], e1 = offsets[node + 1];
  float acc = Yk[(size_t)node * 64 + lane] + selfnorm[node] * tin[(size_t)node * 64 + lane];
  int i = e0;
  for (; i + 4 <= e1; i += 4){
    int r0 = csr_row[i], r1 = csr_row[i+1], r2 = csr_row[i+2], r3 = csr_row[i+3];
    float w0 = csr_norm[i], w1 = csr_norm[i+1], w2 = csr_norm[i+2], w3 = csr_norm[i+3];
    acc += w0 * tin[(size_t)r0 * 64 + lane];
    acc += w1 * tin[(size_t)r1 * 64 + lane];
    acc += w2 * tin[(size_t)r2 * 64 + lane];
    acc += w3 * tin[(size_t)r3 * 64 + lane];
  }
  for (; i < e1; ++i) acc += csr_norm[i] * tin[(size_t)csr_row[i] * 64 + lane];
  tout[(size_t)node * 64 + lane] = acc;
}

// ---------------- relu + bf16 transpose cast ----------------

__global__ void relu_cast_kernel(const float* __restrict__ h, float* __restrict__ outf,
                                 short* __restrict__ embBT, int coloff, int n){
  int idx = blockIdx.x * blockDim.x + threadIdx.x;
  if (idx >= n * 64) return;
  int node = idx >> 6, f = idx & 63;
  float v = h[idx]; v = v > 0.0f ? v : 0.0f;
  outf[idx] = v;
  embBT[(size_t)(coloff + f) * n + node] = f2bf(v);
}

// ---------------- readout GEMM: vsum[n,128] = mask[n,n] @ embBT^T (bf16 MFMA) ----------------
// tile 32 rows x 128 cols, K-chunk 64, 8 waves; grid ceil(n/32)

__global__ __launch_bounds__(512) void readout_kernel(const float* __restrict__ mask,
    const short* __restrict__ embBT, float* __restrict__ vsum, int n){
  __shared__ short Asl[32][72];   // [row][k], 144B rows
  __shared__ short Bsl[128][72];  // [col][k]
  int t = threadIdx.x;
  int w = t >> 6, l = t & 63;
  int g = l >> 4, lr = l & 15;
  int row0 = blockIdx.x * 32;
  int rs = (w & 1) * 16;
  int cs = (w >> 1) * 32;
  f32x4 acc0 = {0,0,0,0}, acc1 = {0,0,0,0};
  for (int k0 = 0; k0 < n; k0 += 64){
    { // stage A (f32 -> bf16): 32 rows x 64 k
      int r = t >> 4, kk = (t & 15) * 4;
      int gr = row0 + r, gk = k0 + kk;
      f32x4 v = {0,0,0,0};
      if (gr < n && gk + 3 < n) v = *(const f32x4*)(mask + (size_t)gr * n + gk);
      short b0 = f2bf(v[0]), b1 = f2bf(v[1]), b2 = f2bf(v[2]), b3 = f2bf(v[3]);
      Asl[r][kk+0] = b0; Asl[r][kk+1] = b1; Asl[r][kk+2] = b2; Asl[r][kk+3] = b3;
    }
    { // stage B: 128 cols x 64 k bf16
      int c = t >> 2, ks = (t & 3) * 16;
      int gk = k0 + ks;
      s16x8 u0 = {0,0,0,0,0,0,0,0}, u1 = {0,0,0,0,0,0,0,0};
      if (gk + 15 < n){
        const short* p = embBT + (size_t)c * n + gk;
        u0 = *(const s16x8*)p; u1 = *(const s16x8*)(p + 8);
      }
      *(s16x8*)&Bsl[c][ks] = u0; *(s16x8*)&Bsl[c][ks + 8] = u1;
    }
    __syncthreads();
    #pragma unroll
    for (int ks = 0; ks < 2; ++ks){
      s16x8 af  = *(const s16x8*)&Asl[rs + lr][ks * 32 + g * 8];
      s16x8 bf0 = *(const s16x8*)&Bsl[cs + lr][ks * 32 + g * 8];
      s16x8 bf1 = *(const s16x8*)&Bsl[cs + 16 + lr][ks * 32 + g * 8];
      acc0 = __builtin_amdgcn_mfma_f32_16x16x32_bf16(af, bf0, acc0, 0, 0, 0);
      acc1 = __builtin_amdgcn_mfma_f32_16x16x32_bf16(af, bf1, acc1, 0, 0, 0);
    }
    __syncthreads();
  }
  #pragma unroll
  for (int i = 0; i < 4; ++i){
    int gr = row0 + rs + g * 4 + i;
    if (gr < n){
      vsum[(size_t)gr * 128 + cs + lr] = acc0[i];
      vsum[(size_t)gr * 128 + cs + 16 + lr] = acc1[i];
    }
  }
}

// ---------------- g = sigmoid(v / ||v||) per 64-dim half ----------------
// (row_sum cancels in normalize: normalize(v/rs) == v/||v||, rs>0)

__global__ __launch_bounds__(256) void gnorm_kernel(const float* __restrict__ vsum,
                                                    float* __restrict__ gbuf, int n){
  int wid = threadIdx.x >> 6, lane = threadIdx.x & 63;
  int node = blockIdx.x * 4 + wid;
  if (node >= n) return;
  float v1 = vsum[(size_t)node * 128 + lane];
  float v2 = vsum[(size_t)node * 128 + 64 + lane];
  float s1 = v1 * v1, s2 = v2 * v2;
  for (int off = 32; off >= 1; off >>= 1){
    s1 += __shfl_xor(s1, off);
    s2 += __shfl_xor(s2, off);
  }
  float i1 = v1 / fmaxf(sqrtf(s1), 1e-12f);
  float i2 = v2 / fmaxf(sqrtf(s2), 1e-12f);
  gbuf[(size_t)node * 128 + lane]      = 1.0f / (1.0f + expf(-i1));
  gbuf[(size_t)node * 128 + 64 + lane] = 1.0f / (1.0f + expf(-i2));
}

// ---------------- bilinear discriminator ----------------
// ret[n]  = [emb·(Wb g1), emb_a·(Wb g1)] + b ; ret_a[n] = [emb_a·(Wb g2), emb·(Wb g2)] + b

__global__ __launch_bounds__(256) void disc_kernel(const float* __restrict__ emb,
    const float* __restrict__ emb_a, const float* __restrict__ gbuf,
    const float* __restrict__ Wb, const float* __restrict__ bptr,
    float* __restrict__ ret, float* __restrict__ reta, int n){
  __shared__ float Wl[64][65];
  int t = threadIdx.x;
  for (int i = t; i < 4096; i += 256) Wl[i >> 6][i & 63] = Wb[i];
  __syncthreads();
  int wid = t >> 6, lane = t & 63;
  int node = blockIdx.x * 4 + wid;
  if (node >= n) return;
  float e1 = emb[(size_t)node * 64 + lane];
  float e2 = emb_a[(size_t)node * 64 + lane];
  float g1 = gbuf[(size_t)node * 128 + lane];
  float g2 = gbuf[(size_t)node * 128 + 64 + lane];
  float u1 = 0.0f, u2 = 0.0f;
  for (int e = 0; e < 64; ++e){
    float wv = Wl[lane][e];
    u1 += wv * __shfl(g1, e);
    u2 += wv * __shfl(g2, e);
  }
  float p1 = e1 * u1, p2 = e2 * u1, p3 = e2 * u2, p4 = e1 * u2;
  for (int off = 32; off >= 1; off >>= 1){
    p1 += __shfl_xor(p1, off); p2 += __shfl_xor(p2, off);
    p3 += __shfl_xor(p3, off); p4 += __shfl_xor(p4, off);
  }
  if (lane == 0){
    float b = bptr[0];
    ret[(size_t)node * 2 + 0]  = p1 + b;
    ret[(size_t)node * 2 + 1]  = p2 + b;
    reta[(size_t)node * 2 + 0] = p3 + b;
    reta[(size_t)node * 2 + 1] = p4 + b;
  }
}

// ---------------- launch ----------------

extern "C" void kernel_launch(void* const* d_in, const int* in_sizes, int n_in,
                              void* d_out, int out_size, void* d_ws, size_t ws_size,
                              hipStream_t stream) {
  const float* feat   = (const float*)d_in[0];
  const float* feat_a = (const float*)d_in[1];
  const int*   ei     = (const int*)d_in[2];
  const float* mask   = (const float*)d_in[3];
  const float* W      = (const float*)d_in[4];
  const float* Wb     = (const float*)d_in[5];
  const float* bsc    = (const float*)d_in[6];
  const int n = in_sizes[0] / F_IN;      // 10000
  const int E = in_sizes[2] / 2;         // 640000
  const size_t sl = (size_t)n * F_OUT;   // slab elements

  float* out  = (float*)d_out;
  float* ret  = out + (size_t)n * F_OUT;
  float* reta = ret + (size_t)n * 2;

  char* wsb = (char*)d_ws;
  size_t off = 0;
  #define WSALLOC(ptr, T, cnt) T* ptr = (T*)(wsb + off); off = (off + sizeof(T)*(size_t)(cnt) + 255) & ~(size_t)255
  WSALLOC(deg, int, n);
  WSALLOC(counts, int, n);
  WSALLOC(offs, int, n + 1);
  WSALLOC(cursors, int, n);
  WSALLOC(dis, float, n);
  WSALLOC(selfnorm, float, n);
  WSALLOC(csr_row, int, E);
  WSALLOC(csr_norm, float, E);
  WSALLOC(Y,  float, sl * 5);
  WSALLOC(Ya, float, sl * 5);
  WSALLOC(u0, float, sl);
  WSALLOC(u1, float, sl);
  WSALLOC(emb_a, float, sl);
  WSALLOC(embBT, short, (size_t)2 * F_OUT * n);
  WSALLOC(vsum, float, (size_t)n * 128);
  WSALLOC(gbuf, float, (size_t)n * 128);
  (void)ws_size; (void)n_in; (void)out_size;

  hipMemsetAsync(deg, 0, (size_t)n * 4, stream);
  hipMemsetAsync(counts, 0, (size_t)n * 4, stream);

  int eb = (E + 255) / 256;
  hist_kernel<<<eb, 256, 0, stream>>>(ei, E, deg, counts);
  dis_kernel<<<(n + 255) / 256, 256, 0, stream>>>(deg, dis, selfnorm, n);
  scan_kernel<<<1, 1024, 0, stream>>>(counts, offs, cursors, n);
  fill_kernel<<<eb, 256, 0, stream>>>(ei, E, dis, cursors, csr_row, csr_norm);

  dim3 fg((n + 63) / 64, 5);
  fgemm_kernel<<<fg, 256, 0, stream>>>(feat,   W, Y,  n);
  fgemm_kernel<<<fg, 256, 0, stream>>>(feat_a, W, Ya, n);

  int gb = (n + 3) / 4;
  // Horner for feat: h = S0 + A(S1 + A(S2 + A(S3 + A*S4)))
  gather_kernel<<<gb, 256, 0, stream>>>(Y + 3 * sl, Y + 4 * sl, offs, csr_row, csr_norm, selfnorm, u0, n);
  gather_kernel<<<gb, 256, 0, stream>>>(Y + 2 * sl, u0, offs, csr_row, csr_norm, selfnorm, u1, n);
  gather_kernel<<<gb, 256, 0, stream>>>(Y + 1 * sl, u1, offs, csr_row, csr_norm, selfnorm, u0, n);
  gather_kernel<<<gb, 256, 0, stream>>>(Y + 0 * sl, u0, offs, csr_row, csr_norm, selfnorm, u1, n);
  relu_cast_kernel<<<(n * 64 + 255) / 256, 256, 0, stream>>>(u1, out, embBT, 0, n);
  // feat_a
  gather_kernel<<<gb, 256, 0, stream>>>(Ya + 3 * sl, Ya + 4 * sl, offs, csr_row, csr_norm, selfnorm, u0, n);
  gather_kernel<<<gb, 256, 0, stream>>>(Ya + 2 * sl, u0, offs, csr_row, csr_norm, selfnorm, u1, n);
  gather_kernel<<<gb, 256, 0, stream>>>(Ya + 1 * sl, u1, offs, csr_row, csr_norm, selfnorm, u0, n);
  gather_kernel<<<gb, 256, 0, stream>>>(Ya + 0 * sl, u0, offs, csr_row, csr_norm, selfnorm, u1, n);
  relu_cast_kernel<<<(n * 64 + 255) / 256, 256, 0, stream>>>(u1, emb_a, embBT, 64, n);

  readout_kernel<<<(n + 31) / 32, 512, 0, stream>>>(mask, embBT, vsum, n);
  gnorm_kernel<<<gb, 256, 0, stream>>>(vsum, gbuf, n);
  disc_kernel<<<gb, 256, 0, stream>>>(out, emb_a, gbuf, Wb, bsc, ret, reta, n);
}